// Round 1
// baseline (6681.125 us; speedup 1.0000x reference)
//
#include <hip/hip_runtime.h>
#include <math.h>

#define NB 1024
#define NT 120
#define NE 50
#define NH 300
#define NC 5
#define NK 350        // NE + NH
#define GH 1200       // 4*NH

// ---------------------------------------------------------------------------
// Loss helper: compute CE for 64 batch rows (mb0..mb0+63) at time tloss from a
// fully-computed h buffer. Two phases with a __syncthreads() between them
// (caller provides the barrier so barrier counts stay block-uniform).
// llds layout: [bb][q][c] -> llds[bb*20 + q*5 + c]
// ---------------------------------------------------------------------------
__device__ __forceinline__ void loss_phase0(
    const float* __restrict__ h, int mb0,
    const float* __restrict__ U, float* __restrict__ llds, int tid)
{
    const int q = tid & 3;          // k-slice
    const int bb = tid >> 2;        // 0..63
    const int b = mb0 + bb;
    const float* hp = h + b * NH;
    float p0 = 0.f, p1 = 0.f, p2 = 0.f, p3 = 0.f, p4 = 0.f;
    // interleaved k = q, q+4, q+8, ... (75 values) for better coalescing
    for (int k = q; k < NH; k += 4) {
        const float hv = hp[k];
        const float* Ur = U + k * NC;
        p0 += hv * Ur[0];
        p1 += hv * Ur[1];
        p2 += hv * Ur[2];
        p3 += hv * Ur[3];
        p4 += hv * Ur[4];
    }
    float* dst = llds + bb * 20 + q * 5;
    dst[0] = p0; dst[1] = p1; dst[2] = p2; dst[3] = p3; dst[4] = p4;
}

__device__ __forceinline__ void loss_phase1(
    int mb0, int tloss,
    const int* __restrict__ labels, const int* __restrict__ mask,
    const float* __restrict__ b2, float* __restrict__ ce_arr,
    const float* __restrict__ llds, int tid)
{
    if (tid >= 64) return;
    const int bb = tid;
    const int b = mb0 + bb;
    const float* src = llds + bb * 20;
    float l0 = src[0] + src[5] + src[10] + src[15] + b2[0];
    float l1 = src[1] + src[6] + src[11] + src[16] + b2[1];
    float l2 = src[2] + src[7] + src[12] + src[17] + b2[2];
    float l3 = src[3] + src[8] + src[13] + src[18] + b2[3];
    float l4 = src[4] + src[9] + src[14] + src[19] + b2[4];
    float m = fmaxf(fmaxf(fmaxf(l0, l1), fmaxf(l2, l3)), l4);
    float s = expf(l0 - m) + expf(l1 - m) + expf(l2 - m) +
              expf(l3 - m) + expf(l4 - m);
    float lse = m + logf(s);
    const int lab = labels[b * NT + tloss];
    const int mk  = mask[b * NT + tloss];
    float ll = (lab == 0) ? l0 : (lab == 1) ? l1 : (lab == 2) ? l2
             : (lab == 3) ? l3 : l4;
    ce_arr[b * NT + tloss] = mk ? (lse - ll) : 0.f;
}

// ---------------------------------------------------------------------------
// One LSTM time step.
// Grid: (16 mtiles, 19 htiles), block 256 threads.
// Block (mtile, htile): computes z for b in [mtile*64, +64), hidx in
// [htile*16, +16), all 4 gates, then the cell update. Thread (bq, hcol)
// owns b = mb0+bq*4+{0..3}, hidx = hbase+hcol, gates i,j,f,o.
// htile==0 blocks additionally compute CE for step t-1 from h_in.
// ---------------------------------------------------------------------------
__global__ __launch_bounds__(256)
void lstm_step_kernel(const int* __restrict__ tokens,
                      const int* __restrict__ labels,
                      const int* __restrict__ mask,
                      const float* __restrict__ emb,
                      const float* __restrict__ Wx,
                      const float* __restrict__ Wh,
                      const float* __restrict__ bias,
                      const float* __restrict__ U,
                      const float* __restrict__ b2,
                      const float* __restrict__ h_in,
                      float* __restrict__ h_out,
                      float* __restrict__ c_buf,
                      float* __restrict__ ce_arr,
                      int t)
{
    __shared__ __align__(16) float a_lds[16][68];   // [kk][bb], padded rows
    __shared__ __align__(16) float w_lds[16][64];   // [kk][hcol*4+g]
    __shared__ float llds[64 * 20];
    __shared__ int tok_lds[64];

    const int tid   = threadIdx.x;
    const int mtile = blockIdx.x;
    const int htile = blockIdx.y;
    const int mb0   = mtile * 64;
    const int hbase = htile * 16;

    if (tid < 64) tok_lds[tid] = tokens[(mb0 + tid) * NT + t];

    const bool do_loss = (htile == 0) && (t > 0);
    if (do_loss) loss_phase0(h_in, mb0, U, llds, tid);
    __syncthreads();
    if (do_loss) loss_phase1(mb0, t - 1, labels, mask, b2, ce_arr, llds, tid);

    const int bq   = tid >> 4;   // 0..15 -> 4 b's each
    const int hcol = tid & 15;   // 0..15

    float acc[4][4];
#pragma unroll
    for (int r = 0; r < 4; ++r)
#pragma unroll
        for (int g = 0; g < 4; ++g) acc[r][g] = 0.f;

    for (int k0 = 0; k0 < NK; k0 += 16) {
        const int kc = (NK - k0) < 16 ? (NK - k0) : 16;

        // ---- stage A tile: a_lds[kk][bb] = [x_t | h_in][b][k0+kk] ----
#pragma unroll
        for (int j = 0; j < 4; ++j) {
            const int idx = tid + j * 256;
            const int kk = idx & 15;
            const int bb = idx >> 4;
            const int k = k0 + kk;
            float v = 0.f;
            if (kk < kc) {
                if (k < NE) v = emb[tok_lds[bb] * NE + k];
                else        v = h_in[(mb0 + bb) * NH + (k - NE)];
            }
            a_lds[kk][bb] = v;
        }

        // ---- stage W tile: w_lds[kk][hc*4+g] = W[k0+kk][g*NH + hbase+hc] ----
#pragma unroll
        for (int j = 0; j < 4; ++j) {
            const int idx = tid + j * 256;
            const int kk  = idx >> 6;
            const int col = idx & 63;
            const int g   = col & 3;
            const int hc  = col >> 2;
            const int k = k0 + kk;
            const int hidx = hbase + hc;
            float v = 0.f;
            if (kk < kc && hidx < NH) {
                const int cidx = g * NH + hidx;
                v = (k < NE) ? Wx[k * GH + cidx] : Wh[(k - NE) * GH + cidx];
            }
            w_lds[kk][col] = v;
        }
        __syncthreads();

        // ---- FMA: acc[r][g] += a[bq*4+r] * w[hcol][g] ----
#pragma unroll
        for (int kk = 0; kk < 16; ++kk) {
            const float4 a4 = *reinterpret_cast<const float4*>(&a_lds[kk][bq * 4]);
            const float4 w4 = *reinterpret_cast<const float4*>(&w_lds[kk][hcol * 4]);
            const float ar[4] = {a4.x, a4.y, a4.z, a4.w};
            const float wr[4] = {w4.x, w4.y, w4.z, w4.w};
#pragma unroll
            for (int r = 0; r < 4; ++r)
#pragma unroll
                for (int g = 0; g < 4; ++g) acc[r][g] += ar[r] * wr[g];
        }
        __syncthreads();
    }

    // ---- LSTM cell update ----
    const int hidx = hbase + hcol;
    if (hidx < NH) {
        const float bi = bias[hidx];
        const float bj = bias[NH + hidx];
        const float bf = bias[2 * NH + hidx];
        const float bo = bias[3 * NH + hidx];
#pragma unroll
        for (int r = 0; r < 4; ++r) {
            const int b = mb0 + bq * 4 + r;
            const float zi = acc[r][0] + bi;
            const float zj = acc[r][1] + bj;
            const float zf = acc[r][2] + bf;
            const float zo = acc[r][3] + bo;
            const float c_old = c_buf[b * NH + hidx];
            const float fg = 1.f / (1.f + expf(-(zf + 1.f)));   // forget bias 1.0
            const float ig = 1.f / (1.f + expf(-zi));
            const float og = 1.f / (1.f + expf(-zo));
            const float c_new = fg * c_old + ig * tanhf(zj);
            const float h_new = og * tanhf(c_new);
            c_buf[b * NH + hidx] = c_new;
            h_out[b * NH + hidx] = h_new;
        }
    }
}

// ---------------------------------------------------------------------------
// CE for the final step (t = NT-1). Grid 16 blocks x 256 threads.
// ---------------------------------------------------------------------------
__global__ __launch_bounds__(256)
void final_loss_kernel(const float* __restrict__ h,
                       const int* __restrict__ labels,
                       const int* __restrict__ mask,
                       const float* __restrict__ U,
                       const float* __restrict__ b2,
                       float* __restrict__ ce_arr)
{
    __shared__ float llds[64 * 20];
    const int tid = threadIdx.x;
    const int mb0 = blockIdx.x * 64;
    loss_phase0(h, mb0, U, llds, tid);
    __syncthreads();
    loss_phase1(mb0, NT - 1, labels, mask, b2, ce_arr, llds, tid);
}

// ---------------------------------------------------------------------------
// Deterministic two-stage reduction: sum(ce) and sum(mask) -> loss.
// ---------------------------------------------------------------------------
__global__ __launch_bounds__(256)
void reduce1_kernel(const float* __restrict__ ce_arr,
                    const int* __restrict__ mask,
                    float* __restrict__ pce, float* __restrict__ pm)
{
    __shared__ float s_ce[256];
    __shared__ float s_m[256];
    const int tid = threadIdx.x;
    const int lo = blockIdx.x * 480;           // 122880 / 256 = 480 exactly
    float ac = 0.f, am = 0.f;
    for (int i = lo + tid; i < lo + 480; i += 256) {
        ac += ce_arr[i];
        am += (float)mask[i];
    }
    s_ce[tid] = ac; s_m[tid] = am;
    __syncthreads();
    for (int s = 128; s > 0; s >>= 1) {
        if (tid < s) { s_ce[tid] += s_ce[tid + s]; s_m[tid] += s_m[tid + s]; }
        __syncthreads();
    }
    if (tid == 0) { pce[blockIdx.x] = s_ce[0]; pm[blockIdx.x] = s_m[0]; }
}

__global__ __launch_bounds__(256)
void reduce2_kernel(const float* __restrict__ pce,
                    const float* __restrict__ pm,
                    float* __restrict__ out)
{
    __shared__ float s_ce[256];
    __shared__ float s_m[256];
    const int tid = threadIdx.x;
    s_ce[tid] = pce[tid];
    s_m[tid]  = pm[tid];
    __syncthreads();
    for (int s = 128; s > 0; s >>= 1) {
        if (tid < s) { s_ce[tid] += s_ce[tid + s]; s_m[tid] += s_m[tid + s]; }
        __syncthreads();
    }
    if (tid == 0) out[0] = s_ce[0] / s_m[0];
}

// ---------------------------------------------------------------------------
extern "C" void kernel_launch(void* const* d_in, const int* in_sizes, int n_in,
                              void* d_out, int out_size, void* d_ws, size_t ws_size,
                              hipStream_t stream)
{
    const int*   tokens = (const int*)d_in[0];
    const int*   labels = (const int*)d_in[1];
    const int*   mask   = (const int*)d_in[2];
    const float* emb    = (const float*)d_in[3];
    const float* Wx     = (const float*)d_in[4];
    const float* Wh     = (const float*)d_in[5];
    const float* bias   = (const float*)d_in[6];
    const float* U      = (const float*)d_in[7];
    const float* b2     = (const float*)d_in[8];
    float* out = (float*)d_out;

    float* ws  = (float*)d_ws;
    float* h0  = ws;                    // NB*NH
    float* h1  = h0 + NB * NH;          // NB*NH
    float* cb  = h1 + NB * NH;          // NB*NH
    float* ce  = cb + NB * NH;          // NB*NT
    float* pce = ce + NB * NT;          // 256
    float* pm  = pce + 256;             // 256

    hipMemsetAsync(h0, 0, NB * NH * sizeof(float), stream);
    hipMemsetAsync(cb, 0, NB * NH * sizeof(float), stream);

    dim3 grid(16, 19);
    for (int t = 0; t < NT; ++t) {
        const float* hin = (t & 1) ? h1 : h0;
        float*      hout = (t & 1) ? h0 : h1;
        lstm_step_kernel<<<grid, 256, 0, stream>>>(
            tokens, labels, mask, emb, Wx, Wh, bias, U, b2,
            hin, hout, cb, ce, t);
    }
    // after t=119 (odd), the last h was written to h0
    final_loss_kernel<<<16, 256, 0, stream>>>(h0, labels, mask, U, b2, ce);
    reduce1_kernel<<<256, 256, 0, stream>>>(ce, mask, pce, pm);
    reduce2_kernel<<<1, 256, 0, stream>>>(pce, pm, out);
}

// Round 2
// 4443.969 us; speedup vs baseline: 1.5034x; 1.5034x over previous
//
#include <hip/hip_runtime.h>
#include <hip/hip_bf16.h>
#include <math.h>

#define NBATCH 1024
#define NT 120
#define NE 50
#define NH 300
#define NC 5
#define GH 1200
#define NKPAD 352      // K = NH + NE padded to 352
#define NSTRIP 15      // hidx strips of 20
#define HS 20          // hidx per strip
#define SCOL 80        // strip cols = 4*HS (gates interleaved: col = 4*hsub+g)
#define NGRP 16        // batch groups
#define BB 64          // batch rows per group
#define ASTR 360       // A_lds row stride in ushorts (conflict-free b128)
#define WSTR 360
#define ZSTR 84        // z_lds row stride in floats (16B-aligned float4 reads)
#define HBSTR 304      // hbuf row stride in ushorts (16B rows)

typedef __attribute__((ext_vector_type(8))) short short8;
typedef __attribute__((ext_vector_type(4))) float f32x4;
typedef __attribute__((ext_vector_type(2))) unsigned short us2;

static __device__ __forceinline__ float bf2f(unsigned short u) {
    unsigned int x = ((unsigned int)u) << 16;
    return __builtin_bit_cast(float, x);
}
static __device__ __forceinline__ unsigned short f2bf(float f) {
    __hip_bfloat16 h = __float2bfloat16(f);   // RNE
    return __builtin_bit_cast(unsigned short, h);
}

// ---------------------------------------------------------------------------
// Prepass: swizzle [Wh;Wx] into strip-major bf16: Wswz[s][j][k], j=4*hsub+g,
// k: 0..299 = Wh rows, 300..349 = Wx rows, 350..351 = 0.
// ---------------------------------------------------------------------------
__global__ __launch_bounds__(256)
void wswz_kernel(const float* __restrict__ Wx, const float* __restrict__ Wh,
                 unsigned short* __restrict__ Wswz)
{
    int idx = blockIdx.x * 256 + threadIdx.x;
    if (idx >= NSTRIP * SCOL * NKPAD) return;
    int s = idx / (SCOL * NKPAD);
    int r = idx % (SCOL * NKPAD);
    int j = r / NKPAD, k = r % NKPAD;
    int col = (j & 3) * NH + s * HS + (j >> 2);
    float v = 0.f;
    if (k < NH)           v = Wh[k * GH + col];
    else if (k < NH + NE) v = Wx[(k - NH) * GH + col];
    Wswz[idx] = f2bf(v);
}

// ---------------------------------------------------------------------------
// Persistent LSTM kernel: 240 blocks = 16 batch-groups x 15 strips.
// blockIdx = s*16 + g  ->  all 15 strips of group g on XCD g%8.
// ---------------------------------------------------------------------------
__device__ __forceinline__ void load_h(const unsigned short* __restrict__ hb,
                                       int b0, unsigned short* A_s, int tid)
{
    const int row = tid >> 2, q = tid & 3;
    const unsigned short* src = hb + (size_t)(b0 + row) * HBSTR;
    unsigned short* dst = A_s + row * ASTR;
    for (int jj = q; jj < 37; jj += 4)
        *(uint4*)(dst + jj * 8) = *(const uint4*)(src + jj * 8);
    if (q == 1)   // tail k=296..299
        *(uint2*)(dst + 296) = *(const uint2*)(src + 296);
}

__device__ __forceinline__ void load_x(const int* __restrict__ tokens,
                                       const float* __restrict__ emb,
                                       int b0, int t, unsigned short* A_s, int tid)
{
    const int row = tid >> 2, q = tid & 3;
    const int tok = tokens[(b0 + row) * NT + t];
    const float* er = emb + (size_t)tok * NE;
    unsigned short* dst = A_s + row * ASTR + NH;   // x at k=300..349
    for (int m = 0; m < 7; ++m) {
        int f = q + 4 * m;                  // float2 index 0..24
        if (f < 25) {
            float2 v = *(const float2*)(er + f * 2);
            us2 o; o.x = f2bf(v.x); o.y = f2bf(v.y);
            *(us2*)(dst + f * 2) = o;
        }
    }
}

__device__ __forceinline__ void do_ce(bool doCE, int tc, int b0, int r0, int nr,
        const unsigned short* A_s, const float* U_s, const float* __restrict__ b2,
        const int* __restrict__ labels, const int* __restrict__ mask,
        float* __restrict__ ce_arr, float* llds, float* lgl, int tid)
{
    // phase 0: partial dot products over h (k 0..299 of A_s, bf16)
    if (doCE && tid < nr * 50) {
        int i = tid / 50, rem = tid % 50, c = rem / 10, q = rem % 10;
        const unsigned short* ar = A_s + (r0 + i) * ASTR + q * 30;
        const float* up = U_s + q * 30 * NC + c;
        float acc = 0.f;
#pragma unroll
        for (int k = 0; k < 30; ++k) acc += bf2f(ar[k]) * up[k * NC];
        llds[i * 50 + c * 10 + q] = acc;
    }
    __syncthreads();
    if (doCE && tid < nr * NC) {
        int i = tid / NC, c = tid % NC;
        const float* pp = llds + i * 50 + c * 10;
        float sum = pp[0]+pp[1]+pp[2]+pp[3]+pp[4]+pp[5]+pp[6]+pp[7]+pp[8]+pp[9];
        lgl[i * NC + c] = sum + b2[c];
    }
    __syncthreads();
    if (doCE && tid < nr) {
        const float* L = lgl + tid * NC;
        float m = fmaxf(fmaxf(fmaxf(L[0], L[1]), fmaxf(L[2], L[3])), L[4]);
        float ssum = expf(L[0]-m)+expf(L[1]-m)+expf(L[2]-m)+expf(L[3]-m)+expf(L[4]-m);
        float lse = m + logf(ssum);
        int bidx = b0 + r0 + tid;
        int lab = labels[bidx * NT + tc];
        int mk  = mask[bidx * NT + tc];
        ce_arr[bidx * NT + tc] = mk ? (lse - L[lab]) : 0.f;
    }
}

__global__ __launch_bounds__(256, 1)
void lstm_persist(const int* __restrict__ tokens,
                  const int* __restrict__ labels,
                  const int* __restrict__ mask,
                  const float* __restrict__ emb,
                  const float* __restrict__ bias,
                  const float* __restrict__ U,
                  const float* __restrict__ b2,
                  const unsigned short* __restrict__ Wswz,
                  unsigned short* __restrict__ hbuf,
                  float* __restrict__ ce_arr,
                  int* __restrict__ cnt)
{
    __shared__ unsigned short A_s[BB * ASTR];     // [h(0..299) | x(300..349) | 0]
    __shared__ unsigned short W_s[SCOL * WSTR];
    __shared__ float z_s[BB * ZSTR];
    __shared__ float c_s[BB * HS];
    __shared__ float U_s[NH * NC];
    __shared__ float b_s[SCOL];
    __shared__ float llds[5 * 50];
    __shared__ float lgl[32];

    const int tid  = threadIdx.x;
    const int g    = blockIdx.x & 15;
    const int s    = blockIdx.x >> 4;
    const int b0   = g * BB;
    const int wave = tid >> 6;
    const int lane = tid & 63;
    const int c15  = lane & 15;
    const int kq   = lane >> 4;
    const int r0   = (s * BB) / NSTRIP;
    const int r1   = ((s + 1) * BB) / NSTRIP;
    const int nr   = r1 - r0;

    // ---- one-time init ----
    for (int idx = tid; idx < SCOL * 44; idx += 256) {        // W strip -> LDS
        int j = idx / 44, ch = idx % 44;
        *(uint4*)(W_s + j * WSTR + ch * 8) =
            *(const uint4*)(Wswz + (size_t)s * SCOL * NKPAD + j * NKPAD + ch * 8);
    }
    for (int idx = tid; idx < BB * NH; idx += 256) {          // zero h region
        int row = idx / NH, k = idx % NH;
        A_s[row * ASTR + k] = 0;
    }
    for (int idx = tid; idx < BB * 10; idx += 256) {          // zero pad k=350..359
        int row = idx / 10, k = 350 + idx % 10;
        A_s[row * ASTR + k] = 0;
    }
    for (int idx = tid; idx < BB * HS; idx += 256) c_s[idx] = 0.f;
    for (int idx = tid; idx < NH * NC; idx += 256) U_s[idx] = U[idx];
    if (tid < SCOL) b_s[tid] = bias[(tid & 3) * NH + s * HS + (tid >> 2)];
    load_x(tokens, emb, b0, 0, A_s, tid);
    __syncthreads();

    const unsigned short* Ab = A_s + (wave * 16 + c15) * ASTR + kq * 8;
    const unsigned short* Wb = W_s + c15 * WSTR + kq * 8;

    for (int t = 0; t < NT; ++t) {
        // ---- CE for step t-1 (h_{t-1} is in A_s) ----
        do_ce(t >= 1, t - 1, b0, r0, nr, A_s, U_s, b2, labels, mask,
              ce_arr, llds, lgl, tid);

        // ---- K-loop: z-strip = A(64x352) @ Wstrip(352x80) ----
        f32x4 acc[5];
#pragma unroll
        for (int n = 0; n < 5; ++n) acc[n] = (f32x4){0.f, 0.f, 0.f, 0.f};
#pragma unroll
        for (int ks = 0; ks < 11; ++ks) {
            short8 av = *(const short8*)(Ab + ks * 32);
#pragma unroll
            for (int n = 0; n < 5; ++n) {
                short8 bv = *(const short8*)(Wb + n * 16 * WSTR + ks * 32);
                acc[n] = __builtin_amdgcn_mfma_f32_16x16x32_bf16(av, bv, acc[n], 0, 0, 0);
            }
        }
#pragma unroll
        for (int n = 0; n < 5; ++n)
#pragma unroll
            for (int j = 0; j < 4; ++j)
                z_s[(wave * 16 + kq * 4 + j) * ZSTR + n * 16 + c15] = acc[n][j];
        __syncthreads();

        // ---- cell update: 1280 (row,hsub) pairs, 5 per thread ----
        unsigned short* hb = hbuf + (size_t)(t & 1) * (NBATCH * HBSTR);
#pragma unroll
        for (int ii = 0; ii < 5; ++ii) {
            int idx = tid * 5 + ii;
            int row = idx / HS, h = idx % HS;
            f32x4 z4 = *(f32x4*)(z_s + row * ZSTR + h * 4);
            float zi = z4[0] + b_s[4 * h + 0];
            float zj = z4[1] + b_s[4 * h + 1];
            float zf = z4[2] + b_s[4 * h + 2];
            float zo = z4[3] + b_s[4 * h + 3];
            float co = c_s[idx];
            float fg = 1.f / (1.f + expf(-(zf + 1.f)));   // forget bias 1.0
            float ig = 1.f / (1.f + expf(-zi));
            float og = 1.f / (1.f + expf(-zo));
            float cn = fg * co + ig * tanhf(zj);
            float hn = og * tanhf(cn);
            c_s[idx] = cn;
            hb[(size_t)(b0 + row) * HBSTR + s * HS + h] = f2bf(hn);
        }

        // ---- intra-XCD group barrier (15 strips of this group) ----
        __threadfence();
        __syncthreads();
        if (tid == 0) {
            __hip_atomic_fetch_add(&cnt[t * NGRP + g], 1,
                                   __ATOMIC_RELEASE, __HIP_MEMORY_SCOPE_AGENT);
            int v; long guard = 0;
            do {
                v = __hip_atomic_load(&cnt[t * NGRP + g],
                                      __ATOMIC_ACQUIRE, __HIP_MEMORY_SCOPE_AGENT);
                if (v < NSTRIP) __builtin_amdgcn_s_sleep(2);
            } while (v < NSTRIP && ++guard < (1L << 24));
        }
        __syncthreads();

        // ---- rebuild A: h_t from group slab, x_{t+1} gather ----
        load_h(hbuf + (size_t)(t & 1) * (NBATCH * HBSTR), b0, A_s, tid);
        if (t + 1 < NT) load_x(tokens, emb, b0, t + 1, A_s, tid);
        __syncthreads();
    }

    // ---- CE for final step (h_119 in A_s) ----
    do_ce(true, NT - 1, b0, r0, nr, A_s, U_s, b2, labels, mask,
          ce_arr, llds, lgl, tid);
}

// ---------------------------------------------------------------------------
// Deterministic two-stage reduction: sum(ce) / sum(mask).
// ---------------------------------------------------------------------------
__global__ __launch_bounds__(256)
void reduce1_kernel(const float* __restrict__ ce_arr,
                    const int* __restrict__ mask,
                    float* __restrict__ pce, float* __restrict__ pm)
{
    __shared__ float s_ce[256];
    __shared__ float s_m[256];
    const int tid = threadIdx.x;
    const int lo = blockIdx.x * 480;     // 122880 / 256
    float ac = 0.f, am = 0.f;
    for (int i = lo + tid; i < lo + 480; i += 256) {
        ac += ce_arr[i];
        am += (float)mask[i];
    }
    s_ce[tid] = ac; s_m[tid] = am;
    __syncthreads();
    for (int s = 128; s > 0; s >>= 1) {
        if (tid < s) { s_ce[tid] += s_ce[tid + s]; s_m[tid] += s_m[tid + s]; }
        __syncthreads();
    }
    if (tid == 0) { pce[blockIdx.x] = s_ce[0]; pm[blockIdx.x] = s_m[0]; }
}

__global__ __launch_bounds__(256)
void reduce2_kernel(const float* __restrict__ pce,
                    const float* __restrict__ pm,
                    float* __restrict__ out)
{
    __shared__ float s_ce[256];
    __shared__ float s_m[256];
    const int tid = threadIdx.x;
    s_ce[tid] = pce[tid];
    s_m[tid]  = pm[tid];
    __syncthreads();
    for (int s = 128; s > 0; s >>= 1) {
        if (tid < s) { s_ce[tid] += s_ce[tid + s]; s_m[tid] += s_m[tid + s]; }
        __syncthreads();
    }
    if (tid == 0) out[0] = s_ce[0] / s_m[0];
}

// ---------------------------------------------------------------------------
extern "C" void kernel_launch(void* const* d_in, const int* in_sizes, int n_in,
                              void* d_out, int out_size, void* d_ws, size_t ws_size,
                              hipStream_t stream)
{
    const int*   tokens = (const int*)d_in[0];
    const int*   labels = (const int*)d_in[1];
    const int*   mask   = (const int*)d_in[2];
    const float* emb    = (const float*)d_in[3];
    const float* Wx     = (const float*)d_in[4];
    const float* Wh     = (const float*)d_in[5];
    const float* bias   = (const float*)d_in[6];
    const float* U      = (const float*)d_in[7];
    const float* b2     = (const float*)d_in[8];

    char* wsb = (char*)d_ws;
    unsigned short* Wswz = (unsigned short*)wsb;                      // 844800 B
    unsigned short* hbuf = (unsigned short*)(wsb + 844800);           // 1245184 B
    float* ce  = (float*)(wsb + 2089984);                             // 491520 B
    float* pce = (float*)(wsb + 2581504);                             // 1024 B
    float* pm  = (float*)(wsb + 2582528);                             // 1024 B
    int*   cnt = (int*)(wsb + 2583552);                               // 7680 B

    hipMemsetAsync(cnt, 0, NT * NGRP * sizeof(int), stream);
    wswz_kernel<<<(NSTRIP * SCOL * NKPAD + 255) / 256, 256, 0, stream>>>(Wx, Wh, Wswz);
    lstm_persist<<<NGRP * NSTRIP, 256, 0, stream>>>(
        tokens, labels, mask, emb, bias, U, b2, Wswz, hbuf, ce, cnt);
    reduce1_kernel<<<256, 256, 0, stream>>>(ce, mask, pce, pm);
    reduce2_kernel<<<1, 256, 0, stream>>>(pce, pm, (float*)d_out);
}

// Round 3
// 892.690 us; speedup vs baseline: 7.4843x; 4.9782x over previous
//
#include <hip/hip_runtime.h>
#include <hip/hip_bf16.h>
#include <math.h>

#define NBATCH 1024
#define NT 120
#define NE 50
#define NH 300
#define NC 5
#define GH 1200
#define NKPAD 352      // K = NH + NE padded to 352
#define NSTRIP 15      // hidx strips of 20
#define HS 20          // hidx per strip
#define SCOL 80        // strip cols = 4*HS (gates interleaved: col = 4*hsub+g)
#define NGRP 16        // batch groups
#define BB 64          // batch rows per group
#define ASTR 360       // A_lds row stride in ushorts (conflict-free b128)
#define WSTR 360
#define ZSTR 84        // z_lds row stride in floats (16B-aligned float4 reads)
#define HBSTR 304      // hbuf row stride in ushorts (608B rows, 76 x 8B chunks)
#define HCH 76         // 8B chunks per hbuf row
#define NCHUNK 4800    // 64 rows x 75 chunks of live h data

typedef __attribute__((ext_vector_type(8))) short short8;
typedef __attribute__((ext_vector_type(4))) float f32x4;
typedef __attribute__((ext_vector_type(2))) unsigned short us2;

static __device__ __forceinline__ float bf2f(unsigned short u) {
    unsigned int x = ((unsigned int)u) << 16;
    return __builtin_bit_cast(float, x);
}
static __device__ __forceinline__ unsigned short f2bf(float f) {
    __hip_bfloat16 h = __float2bfloat16(f);   // RNE
    return __builtin_bit_cast(unsigned short, h);
}

// Device-visible 2B store: write-through to MALL (no L2 coherence reliance).
static __device__ __forceinline__ void st_short_dev(unsigned short* p,
                                                    unsigned short v) {
    unsigned int vv = v;
    asm volatile("global_store_short %0, %1, off sc0 sc1"
                 :: "v"(p), "v"(vv) : "memory");
}

// ---------------------------------------------------------------------------
// Prepass: swizzle [Wh;Wx] into strip-major bf16: Wswz[s][j][k], j=4*hsub+g,
// k: 0..299 = Wh rows, 300..349 = Wx rows, 350..351 = 0.
// ---------------------------------------------------------------------------
__global__ __launch_bounds__(256)
void wswz_kernel(const float* __restrict__ Wx, const float* __restrict__ Wh,
                 unsigned short* __restrict__ Wswz)
{
    int idx = blockIdx.x * 256 + threadIdx.x;
    if (idx >= NSTRIP * SCOL * NKPAD) return;
    int s = idx / (SCOL * NKPAD);
    int r = idx % (SCOL * NKPAD);
    int j = r / NKPAD, k = r % NKPAD;
    int col = (j & 3) * NH + s * HS + (j >> 2);
    float v = 0.f;
    if (k < NH)           v = Wh[k * GH + col];
    else if (k < NH + NE) v = Wx[(k - NH) * GH + col];
    Wswz[idx] = f2bf(v);
}

// ---------------------------------------------------------------------------
// load_h: pull the group's full h slab (64 x 300 bf16) from hbuf into A_s.
// Device-scope (sc1) 8B atomic loads, 19-deep static pipeline per thread.
// ---------------------------------------------------------------------------
__device__ __forceinline__ void load_h(const unsigned short* __restrict__ hb,
                                       int b0, unsigned short* A_s, int tid)
{
    const unsigned long long* src =
        (const unsigned long long*)(hb + (size_t)b0 * HBSTR);
    unsigned long long v[19];
#pragma unroll
    for (int m = 0; m < 19; ++m) {
        const int idx = tid + 256 * m;
        if (idx < NCHUNK) {
            const int row = idx / 75, j = idx % 75;
            v[m] = __hip_atomic_load(src + (size_t)row * HCH + j,
                                     __ATOMIC_RELAXED, __HIP_MEMORY_SCOPE_AGENT);
        }
    }
#pragma unroll
    for (int m = 0; m < 19; ++m) {
        const int idx = tid + 256 * m;
        if (idx < NCHUNK) {
            const int row = idx / 75, j = idx % 75;
            *(unsigned long long*)(A_s + row * ASTR + j * 4) = v[m];
        }
    }
}

__device__ __forceinline__ void load_x(const int* __restrict__ tokens,
                                       const float* __restrict__ emb,
                                       int b0, int t, unsigned short* A_s, int tid)
{
    const int row = tid >> 2, q = tid & 3;
    const int tok = tokens[(b0 + row) * NT + t];
    const float* er = emb + (size_t)tok * NE;
    unsigned short* dst = A_s + row * ASTR + NH;   // x at k=300..349
    for (int m = 0; m < 7; ++m) {
        int f = q + 4 * m;                  // float2 index 0..24
        if (f < 25) {
            float2 v = *(const float2*)(er + f * 2);
            us2 o; o.x = f2bf(v.x); o.y = f2bf(v.y);
            *(us2*)(dst + f * 2) = o;
        }
    }
}

__device__ __forceinline__ void do_ce(bool doCE, int tc, int b0, int r0, int nr,
        const unsigned short* A_s, const float* U_s, const float* __restrict__ b2,
        const int* __restrict__ labels, const int* __restrict__ mask,
        float* __restrict__ ce_arr, float* llds, float* lgl, int tid)
{
    // phase 0: partial dot products over h (k 0..299 of A_s, bf16)
    if (doCE && tid < nr * 50) {
        int i = tid / 50, rem = tid % 50, c = rem / 10, q = rem % 10;
        const unsigned short* ar = A_s + (r0 + i) * ASTR + q * 30;
        const float* up = U_s + q * 30 * NC + c;
        float acc = 0.f;
#pragma unroll
        for (int k = 0; k < 30; ++k) acc += bf2f(ar[k]) * up[k * NC];
        llds[i * 50 + c * 10 + q] = acc;
    }
    __syncthreads();
    if (doCE && tid < nr * NC) {
        int i = tid / NC, c = tid % NC;
        const float* pp = llds + i * 50 + c * 10;
        float sum = pp[0]+pp[1]+pp[2]+pp[3]+pp[4]+pp[5]+pp[6]+pp[7]+pp[8]+pp[9];
        lgl[i * NC + c] = sum + b2[c];
    }
    __syncthreads();
    if (doCE && tid < nr) {
        const float* L = lgl + tid * NC;
        float m = fmaxf(fmaxf(fmaxf(L[0], L[1]), fmaxf(L[2], L[3])), L[4]);
        float ssum = expf(L[0]-m)+expf(L[1]-m)+expf(L[2]-m)+expf(L[3]-m)+expf(L[4]-m);
        float lse = m + logf(ssum);
        int bidx = b0 + r0 + tid;
        int lab = labels[bidx * NT + tc];
        int mk  = mask[bidx * NT + tc];
        ce_arr[bidx * NT + tc] = mk ? (lse - L[lab]) : 0.f;
    }
}

// ---------------------------------------------------------------------------
// Persistent LSTM kernel: 240 blocks = 16 batch-groups x 15 strips.
// ---------------------------------------------------------------------------
__global__ __launch_bounds__(256, 1)
void lstm_persist(const int* __restrict__ tokens,
                  const int* __restrict__ labels,
                  const int* __restrict__ mask,
                  const float* __restrict__ emb,
                  const float* __restrict__ bias,
                  const float* __restrict__ U,
                  const float* __restrict__ b2,
                  const unsigned short* __restrict__ Wswz,
                  unsigned short* __restrict__ hbuf,
                  float* __restrict__ ce_arr,
                  int* __restrict__ cnt)
{
    __shared__ unsigned short A_s[BB * ASTR];     // [h(0..299) | x(300..349) | 0]
    __shared__ unsigned short W_s[SCOL * WSTR];
    __shared__ float z_s[BB * ZSTR];
    __shared__ float c_s[BB * HS];
    __shared__ float U_s[NH * NC];
    __shared__ float b_s[SCOL];
    __shared__ float llds[5 * 50];
    __shared__ float lgl[32];

    const int tid  = threadIdx.x;
    const int g    = blockIdx.x & 15;
    const int s    = blockIdx.x >> 4;
    const int b0   = g * BB;
    const int wave = tid >> 6;
    const int lane = tid & 63;
    const int c15  = lane & 15;
    const int kq   = lane >> 4;
    const int r0   = (s * BB) / NSTRIP;
    const int r1   = ((s + 1) * BB) / NSTRIP;
    const int nr   = r1 - r0;

    // ---- one-time init ----
    for (int idx = tid; idx < SCOL * 44; idx += 256) {        // W strip -> LDS
        int j = idx / 44, ch = idx % 44;
        *(uint4*)(W_s + j * WSTR + ch * 8) =
            *(const uint4*)(Wswz + (size_t)s * SCOL * NKPAD + j * NKPAD + ch * 8);
    }
    for (int idx = tid; idx < BB * NH; idx += 256) {          // zero h region
        int row = idx / NH, k = idx % NH;
        A_s[row * ASTR + k] = 0;
    }
    for (int idx = tid; idx < BB * 10; idx += 256) {          // zero pad k=350..359
        int row = idx / 10, k = 350 + idx % 10;
        A_s[row * ASTR + k] = 0;
    }
    for (int idx = tid; idx < BB * HS; idx += 256) c_s[idx] = 0.f;
    for (int idx = tid; idx < NH * NC; idx += 256) U_s[idx] = U[idx];
    if (tid < SCOL) b_s[tid] = bias[(tid & 3) * NH + s * HS + (tid >> 2)];
    load_x(tokens, emb, b0, 0, A_s, tid);
    __syncthreads();

    const unsigned short* Ab = A_s + (wave * 16 + c15) * ASTR + kq * 8;
    const unsigned short* Wb = W_s + c15 * WSTR + kq * 8;

    for (int t = 0; t < NT; ++t) {
        // ---- CE for step t-1 (h_{t-1} is in A_s) ----
        do_ce(t >= 1, t - 1, b0, r0, nr, A_s, U_s, b2, labels, mask,
              ce_arr, llds, lgl, tid);

        // ---- K-loop: z-strip = A(64x352) @ Wstrip(352x80) ----
        f32x4 acc[5];
#pragma unroll
        for (int n = 0; n < 5; ++n) acc[n] = (f32x4){0.f, 0.f, 0.f, 0.f};
#pragma unroll
        for (int ks = 0; ks < 11; ++ks) {
            short8 av = *(const short8*)(Ab + ks * 32);
#pragma unroll
            for (int n = 0; n < 5; ++n) {
                short8 bv = *(const short8*)(Wb + n * 16 * WSTR + ks * 32);
                acc[n] = __builtin_amdgcn_mfma_f32_16x16x32_bf16(av, bv, acc[n], 0, 0, 0);
            }
        }
#pragma unroll
        for (int n = 0; n < 5; ++n)
#pragma unroll
            for (int j = 0; j < 4; ++j)
                z_s[(wave * 16 + kq * 4 + j) * ZSTR + n * 16 + c15] = acc[n][j];
        __syncthreads();

        // ---- cell update: 1280 (row,hsub) pairs, 5 per thread ----
        unsigned short* hb = hbuf + (size_t)(t & 1) * (NBATCH * HBSTR);
        unsigned short* hp = hb + (size_t)(b0 + (tid >> 2)) * HBSTR
                           + s * HS + (tid & 3) * 5;
#pragma unroll
        for (int ii = 0; ii < 5; ++ii) {
            int idx = tid * 5 + ii;
            int row = idx / HS, h = idx % HS;
            f32x4 z4 = *(f32x4*)(z_s + row * ZSTR + h * 4);
            float zi = z4[0] + b_s[4 * h + 0];
            float zj = z4[1] + b_s[4 * h + 1];
            float zf = z4[2] + b_s[4 * h + 2];
            float zo = z4[3] + b_s[4 * h + 3];
            float co = c_s[idx];
            float fg = 1.f / (1.f + expf(-(zf + 1.f)));   // forget bias 1.0
            float ig = 1.f / (1.f + expf(-zi));
            float og = 1.f / (1.f + expf(-zo));
            float cn = fg * co + ig * tanhf(zj);
            float hn = og * tanhf(cn);
            c_s[idx] = cn;
            st_short_dev(hp + ii, f2bf(hn));   // device-visible, no L2 reliance
        }

        // drain our inline-asm stores (compiler doesn't track them), then
        // block-wide barrier so all h stores are committed before the flag.
        asm volatile("s_waitcnt vmcnt(0)" ::: "memory");
        __syncthreads();

        // ---- group barrier: relaxed atomics only (no wbl2/inv) ----
        if (tid == 0) {
            __hip_atomic_fetch_add(&cnt[t * NGRP + g], 1,
                                   __ATOMIC_RELAXED, __HIP_MEMORY_SCOPE_AGENT);
            int v; int guard = 0;
            do {
                v = __hip_atomic_load(&cnt[t * NGRP + g],
                                      __ATOMIC_RELAXED, __HIP_MEMORY_SCOPE_AGENT);
            } while (v < NSTRIP && ++guard < (1 << 14));
        }
        __syncthreads();

        // ---- rebuild A: h_t from group slab (sc1 loads), x_{t+1} gather ----
        load_h(hbuf + (size_t)(t & 1) * (NBATCH * HBSTR), b0, A_s, tid);
        if (t + 1 < NT) load_x(tokens, emb, b0, t + 1, A_s, tid);
        __syncthreads();
    }

    // ---- CE for final step (h_119 in A_s) ----
    do_ce(true, NT - 1, b0, r0, nr, A_s, U_s, b2, labels, mask,
          ce_arr, llds, lgl, tid);
}

// ---------------------------------------------------------------------------
// Deterministic two-stage reduction: sum(ce) / sum(mask).
// ---------------------------------------------------------------------------
__global__ __launch_bounds__(256)
void reduce1_kernel(const float* __restrict__ ce_arr,
                    const int* __restrict__ mask,
                    float* __restrict__ pce, float* __restrict__ pm)
{
    __shared__ float s_ce[256];
    __shared__ float s_m[256];
    const int tid = threadIdx.x;
    const int lo = blockIdx.x * 480;     // 122880 / 256
    float ac = 0.f, am = 0.f;
    for (int i = lo + tid; i < lo + 480; i += 256) {
        ac += ce_arr[i];
        am += (float)mask[i];
    }
    s_ce[tid] = ac; s_m[tid] = am;
    __syncthreads();
    for (int s = 128; s > 0; s >>= 1) {
        if (tid < s) { s_ce[tid] += s_ce[tid + s]; s_m[tid] += s_m[tid + s]; }
        __syncthreads();
    }
    if (tid == 0) { pce[blockIdx.x] = s_ce[0]; pm[blockIdx.x] = s_m[0]; }
}

__global__ __launch_bounds__(256)
void reduce2_kernel(const float* __restrict__ pce,
                    const float* __restrict__ pm,
                    float* __restrict__ out)
{
    __shared__ float s_ce[256];
    __shared__ float s_m[256];
    const int tid = threadIdx.x;
    s_ce[tid] = pce[tid];
    s_m[tid]  = pm[tid];
    __syncthreads();
    for (int s = 128; s > 0; s >>= 1) {
        if (tid < s) { s_ce[tid] += s_ce[tid + s]; s_m[tid] += s_m[tid + s]; }
        __syncthreads();
    }
    if (tid == 0) out[0] = s_ce[0] / s_m[0];
}

// ---------------------------------------------------------------------------
extern "C" void kernel_launch(void* const* d_in, const int* in_sizes, int n_in,
                              void* d_out, int out_size, void* d_ws, size_t ws_size,
                              hipStream_t stream)
{
    const int*   tokens = (const int*)d_in[0];
    const int*   labels = (const int*)d_in[1];
    const int*   mask   = (const int*)d_in[2];
    const float* emb    = (const float*)d_in[3];
    const float* Wx     = (const float*)d_in[4];
    const float* Wh     = (const float*)d_in[5];
    const float* bias   = (const float*)d_in[6];
    const float* U      = (const float*)d_in[7];
    const float* b2     = (const float*)d_in[8];

    char* wsb = (char*)d_ws;
    unsigned short* Wswz = (unsigned short*)wsb;                      // 844800 B
    unsigned short* hbuf = (unsigned short*)(wsb + 844800);           // 1245184 B
    float* ce  = (float*)(wsb + 2089984);                             // 491520 B
    float* pce = (float*)(wsb + 2581504);                             // 1024 B
    float* pm  = (float*)(wsb + 2582528);                             // 1024 B
    int*   cnt = (int*)(wsb + 2583552);                               // 7680 B

    hipMemsetAsync(cnt, 0, NT * NGRP * sizeof(int), stream);
    wswz_kernel<<<(NSTRIP * SCOL * NKPAD + 255) / 256, 256, 0, stream>>>(Wx, Wh, Wswz);
    lstm_persist<<<NGRP * NSTRIP, 256, 0, stream>>>(
        tokens, labels, mask, emb, bias, U, b2, Wswz, hbuf, ce, cnt);
    reduce1_kernel<<<256, 256, 0, stream>>>(ce, mask, pce, pm);
    reduce2_kernel<<<1, 256, 0, stream>>>(pce, pm, (float*)d_out);
}

// Round 5
// 787.646 us; speedup vs baseline: 8.4824x; 1.1334x over previous
//
#include <hip/hip_runtime.h>
#include <hip/hip_bf16.h>
#include <math.h>

#define NBATCH 1024
#define NT 120
#define NE 50
#define NH 300
#define NC 5
#define GH 1200
#define NKPAD 352      // K = NH + NE padded to 352
#define NSTRIP 15      // hidx strips of 20
#define HS 20          // hidx per strip
#define SCOL 80        // strip cols = 4*HS (gates interleaved: col = 4*hsub+g)
#define NGRP 16        // batch groups
#define BB 64          // batch rows per group
#define ASTR 360       // A_lds row stride in ushorts (conflict-free b128)
#define WSTR 360
#define ZSTR 84        // z_lds row stride in floats (16B-aligned float4 reads)
#define HBSTR 304      // hbuf row stride in ushorts (608B rows)
#define HCH 76         // 8B chunks per hbuf row
#define NCHUNK 4800    // 64 rows x 75 x 8B chunks of live h data

typedef __attribute__((ext_vector_type(8))) short short8;
typedef __attribute__((ext_vector_type(4))) float f32x4;
typedef __attribute__((ext_vector_type(2))) unsigned short us2;

static __device__ __forceinline__ float bf2f(unsigned short u) {
    unsigned int x = ((unsigned int)u) << 16;
    return __builtin_bit_cast(float, x);
}
static __device__ __forceinline__ unsigned short f2bf(float f) {
    __hip_bfloat16 h = __float2bfloat16(f);   // RNE
    return __builtin_bit_cast(unsigned short, h);
}

// ---------------------------------------------------------------------------
// Prepass: swizzle [Wh;Wx] into strip-major bf16: Wswz[s][j][k], j=4*hsub+g,
// k: 0..299 = Wh rows, 300..349 = Wx rows, 350..351 = 0.
// ---------------------------------------------------------------------------
__global__ __launch_bounds__(256)
void wswz_kernel(const float* __restrict__ Wx, const float* __restrict__ Wh,
                 unsigned short* __restrict__ Wswz)
{
    int idx = blockIdx.x * 256 + threadIdx.x;
    if (idx >= NSTRIP * SCOL * NKPAD) return;
    int s = idx / (SCOL * NKPAD);
    int r = idx % (SCOL * NKPAD);
    int j = r / NKPAD, k = r % NKPAD;
    int col = (j & 3) * NH + s * HS + (j >> 2);
    float v = 0.f;
    if (k < NH)           v = Wh[k * GH + col];
    else if (k < NH + NE) v = Wx[(k - NH) * GH + col];
    Wswz[idx] = f2bf(v);
}

// ---------------------------------------------------------------------------
// h slab load (PROVEN round-3 path): agent-scope relaxed 8B atomic loads,
// 19 in flight per thread, then LDS writes.
// ---------------------------------------------------------------------------
__device__ __forceinline__ void load_h(const unsigned short* __restrict__ hb,
                                       int b0, unsigned short* A_s, int tid)
{
    const unsigned long long* src =
        (const unsigned long long*)(hb + (size_t)b0 * HBSTR);
    unsigned long long v[19];
#pragma unroll
    for (int m = 0; m < 19; ++m) {
        const int idx = tid + 256 * m;
        if (idx < NCHUNK) {
            const int row = idx / 75, j = idx % 75;
            v[m] = __hip_atomic_load(src + (size_t)row * HCH + j,
                                     __ATOMIC_RELAXED, __HIP_MEMORY_SCOPE_AGENT);
        }
    }
#pragma unroll
    for (int m = 0; m < 19; ++m) {
        const int idx = tid + 256 * m;
        if (idx < NCHUNK) {
            const int row = idx / 75, j = idx % 75;
            *(unsigned long long*)(A_s + row * ASTR + j * 4) = v[m];
        }
    }
}

// h strip store: 320 coalesced 8B agent-scope stores from the LDS stage.
__device__ __forceinline__ void store_h(unsigned short* hb, int b0, int st,
                                        const unsigned short* h_stage, int tid)
{
#pragma unroll
    for (int m = 0; m < 2; ++m) {
        const int c = tid + m * 256;
        if (c < 320) {
            const int row = c / 5, j = c % 5;
            unsigned long long val =
                *(const unsigned long long*)(h_stage + row * HS + j * 4);
            unsigned long long* p = (unsigned long long*)
                (hb + (size_t)(b0 + row) * HBSTR + st * HS + j * 4);
            __hip_atomic_store(p, val, __ATOMIC_RELAXED,
                               __HIP_MEMORY_SCOPE_AGENT);
        }
    }
}

__device__ __forceinline__ void load_x(const int* __restrict__ tokens,
                                       const float* __restrict__ emb,
                                       int b0, int t, unsigned short* A_s, int tid)
{
    const int row = tid >> 2, q = tid & 3;
    const int tok = tokens[(b0 + row) * NT + t];
    const float* er = emb + (size_t)tok * NE;
    unsigned short* dst = A_s + row * ASTR + NH;   // x at k=300..349
    for (int m = 0; m < 7; ++m) {
        int f = q + 4 * m;                  // float2 index 0..24
        if (f < 25) {
            float2 v = *(const float2*)(er + f * 2);
            us2 o; o.x = f2bf(v.x); o.y = f2bf(v.y);
            *(us2*)(dst + f * 2) = o;
        }
    }
}

__device__ __forceinline__ void do_ce(bool doCE, int tc, int b0, int r0, int nr,
        const unsigned short* A_s, const float* U_s, const float* __restrict__ b2,
        const int* __restrict__ labels, const int* __restrict__ mask,
        float* __restrict__ ce_arr, float* llds, float* lgl, int tid)
{
    if (doCE && tid < nr * 50) {
        int i = tid / 50, rem = tid % 50, c = rem / 10, q = rem % 10;
        const unsigned short* ar = A_s + (r0 + i) * ASTR + q * 30;
        const float* up = U_s + q * 30 * NC + c;
        float acc = 0.f;
#pragma unroll
        for (int k = 0; k < 30; ++k) acc += bf2f(ar[k]) * up[k * NC];
        llds[i * 50 + c * 10 + q] = acc;
    }
    __syncthreads();
    if (doCE && tid < nr * NC) {
        int i = tid / NC, c = tid % NC;
        const float* pp = llds + i * 50 + c * 10;
        float sum = pp[0]+pp[1]+pp[2]+pp[3]+pp[4]+pp[5]+pp[6]+pp[7]+pp[8]+pp[9];
        lgl[i * NC + c] = sum + b2[c];
    }
    __syncthreads();
    if (doCE && tid < nr) {
        const float* L = lgl + tid * NC;
        float m = fmaxf(fmaxf(fmaxf(L[0], L[1]), fmaxf(L[2], L[3])), L[4]);
        float ssum = expf(L[0]-m)+expf(L[1]-m)+expf(L[2]-m)+expf(L[3]-m)+expf(L[4]-m);
        float lse = m + logf(ssum);
        int bidx = b0 + r0 + tid;
        int lab = labels[bidx * NT + tc];
        int mk  = mask[bidx * NT + tc];
        ce_arr[bidx * NT + tc] = mk ? (lse - L[lab]) : 0.f;
    }
}

// ---------------------------------------------------------------------------
// Persistent LSTM kernel: 240 blocks = 16 batch-groups x 15 strips.
// ---------------------------------------------------------------------------
__global__ __launch_bounds__(256, 1)
void lstm_persist(const int* __restrict__ tokens,
                  const int* __restrict__ labels,
                  const int* __restrict__ mask,
                  const float* __restrict__ emb,
                  const float* __restrict__ bias,
                  const float* __restrict__ U,
                  const float* __restrict__ b2,
                  const unsigned short* __restrict__ Wswz,
                  unsigned short* __restrict__ hbuf,
                  float* __restrict__ ce_arr,
                  int* __restrict__ flags)
{
    __shared__ unsigned short A_s[BB * ASTR];     // [h(0..299) | x(300..349) | 0]
    __shared__ unsigned short W_s[SCOL * WSTR];
    __shared__ __align__(16) unsigned short h_stage[BB * HS];
    __shared__ float z_s[BB * ZSTR];
    __shared__ float c_s[BB * HS];
    __shared__ float U_s[NH * NC];
    __shared__ float b_s[SCOL];
    __shared__ float llds[5 * 50];
    __shared__ float lgl[32];

    const int tid  = threadIdx.x;
    const int g    = blockIdx.x & 15;
    const int s    = blockIdx.x >> 4;
    const int b0   = g * BB;
    const int wave = tid >> 6;
    const int lane = tid & 63;
    const int c15  = lane & 15;
    const int kq   = lane >> 4;
    const int r0   = (s * BB) / NSTRIP;
    const int r1   = ((s + 1) * BB) / NSTRIP;
    const int nr   = r1 - r0;

    // ---- one-time init ----
    for (int idx = tid; idx < SCOL * 44; idx += 256) {        // W strip -> LDS
        int j = idx / 44, ch = idx % 44;
        *(uint4*)(W_s + j * WSTR + ch * 8) =
            *(const uint4*)(Wswz + (size_t)s * SCOL * NKPAD + j * NKPAD + ch * 8);
    }
    for (int idx = tid; idx < BB * NH; idx += 256) {          // zero h region
        int row = idx / NH, k = idx % NH;
        A_s[row * ASTR + k] = 0;
    }
    for (int idx = tid; idx < BB * 10; idx += 256) {          // zero pad k=350..359
        int row = idx / 10, k = 350 + idx % 10;
        A_s[row * ASTR + k] = 0;
    }
    for (int idx = tid; idx < BB * HS; idx += 256) c_s[idx] = 0.f;
    for (int idx = tid; idx < NH * NC; idx += 256) U_s[idx] = U[idx];
    if (tid < SCOL) b_s[tid] = bias[(tid & 3) * NH + s * HS + (tid >> 2)];
    load_x(tokens, emb, b0, 0, A_s, tid);
    __syncthreads();

    const unsigned short* Ab = A_s + (wave * 16 + c15) * ASTR + kq * 8;
    const unsigned short* Wb = W_s + c15 * WSTR + kq * 8;

    for (int t = 0; t < NT; ++t) {
        // ---- 1) K-loop: z-strip = A(64x352) @ Wstrip(352x80) ----
        f32x4 acc[5];
#pragma unroll
        for (int n = 0; n < 5; ++n) acc[n] = (f32x4){0.f, 0.f, 0.f, 0.f};
#pragma unroll
        for (int ks = 0; ks < 11; ++ks) {
            short8 av = *(const short8*)(Ab + ks * 32);
#pragma unroll
            for (int n = 0; n < 5; ++n) {
                short8 bv = *(const short8*)(Wb + n * 16 * WSTR + ks * 32);
                acc[n] = __builtin_amdgcn_mfma_f32_16x16x32_bf16(av, bv, acc[n], 0, 0, 0);
            }
        }
#pragma unroll
        for (int n = 0; n < 5; ++n)
#pragma unroll
            for (int j = 0; j < 4; ++j)
                z_s[(wave * 16 + kq * 4 + j) * ZSTR + n * 16 + c15] = acc[n][j];
        __syncthreads();

        // ---- 2) cell update -> c_s + LDS h stage ----
#pragma unroll
        for (int ii = 0; ii < 5; ++ii) {
            int idx = tid * 5 + ii;
            int row = idx / HS, h = idx % HS;
            f32x4 z4 = *(f32x4*)(z_s + row * ZSTR + h * 4);
            float zi = z4[0] + b_s[4 * h + 0];
            float zj = z4[1] + b_s[4 * h + 1];
            float zf = z4[2] + b_s[4 * h + 2];
            float zo = z4[3] + b_s[4 * h + 3];
            float co = c_s[idx];
            float fg = 1.f / (1.f + expf(-(zf + 1.f)));   // forget bias 1.0
            float ig = 1.f / (1.f + expf(-zi));
            float og = 1.f / (1.f + expf(-zo));
            float cn = fg * co + ig * tanhf(zj);
            float hn = og * tanhf(cn);
            c_s[idx] = cn;
            h_stage[idx] = f2bf(hn);
        }
        __syncthreads();

        // ---- 3) coalesced 8B h strip store + drain ----
        unsigned short* hb = hbuf + (size_t)(t & 1) * (NBATCH * HBSTR);
        store_h(hb, b0, s, h_stage, tid);
        asm volatile("s_waitcnt vmcnt(0)" ::: "memory");
        __syncthreads();

        // ---- 4) raise per-strip flag (agent-scope relaxed store) ----
        if (tid == 0)
            __hip_atomic_store(flags + (size_t)(t * NGRP + g) * 16 + s, 1,
                               __ATOMIC_RELAXED, __HIP_MEMORY_SCOPE_AGENT);

        // ---- 5) overlap window: x gather (t+1) + CE(t-1) while flags fly ----
        if (t + 1 < NT) load_x(tokens, emb, b0, t + 1, A_s, tid);
        do_ce(t >= 1, t - 1, b0, r0, nr, A_s, U_s, b2, labels, mask,
              ce_arr, llds, lgl, tid);

        // ---- 6) poll the group's 15 flags (backoff, guarded) ----
        if (tid < NSTRIP) {
            const int* fp = flags + (size_t)(t * NGRP + g) * 16 + tid;
            int fv = 0; int gu = 0;
            do {
                fv = __hip_atomic_load(fp, __ATOMIC_RELAXED,
                                       __HIP_MEMORY_SCOPE_AGENT);
                if (!fv) __builtin_amdgcn_s_sleep(4);
            } while (!fv && ++gu < (1 << 17));
        }
        __syncthreads();

        // ---- 7) pull group h slab into A_s ----
        load_h(hb, b0, A_s, tid);
        __syncthreads();
    }

    // ---- CE for final step (h_119 in A_s) ----
    do_ce(true, NT - 1, b0, r0, nr, A_s, U_s, b2, labels, mask,
          ce_arr, llds, lgl, tid);
}

// ---------------------------------------------------------------------------
// Deterministic two-stage reduction: sum(ce) / sum(mask).
// ---------------------------------------------------------------------------
__global__ __launch_bounds__(256)
void reduce1_kernel(const float* __restrict__ ce_arr,
                    const int* __restrict__ mask,
                    float* __restrict__ pce, float* __restrict__ pm)
{
    __shared__ float s_ce[256];
    __shared__ float s_m[256];
    const int tid = threadIdx.x;
    const int lo = blockIdx.x * 480;     // 122880 / 256
    float ac = 0.f, am = 0.f;
    for (int i = lo + tid; i < lo + 480; i += 256) {
        ac += ce_arr[i];
        am += (float)mask[i];
    }
    s_ce[tid] = ac; s_m[tid] = am;
    __syncthreads();
    for (int r = 128; r > 0; r >>= 1) {
        if (tid < r) { s_ce[tid] += s_ce[tid + r]; s_m[tid] += s_m[tid + r]; }
        __syncthreads();
    }
    if (tid == 0) { pce[blockIdx.x] = s_ce[0]; pm[blockIdx.x] = s_m[0]; }
}

__global__ __launch_bounds__(256)
void reduce2_kernel(const float* __restrict__ pce,
                    const float* __restrict__ pm,
                    float* __restrict__ out)
{
    __shared__ float s_ce[256];
    __shared__ float s_m[256];
    const int tid = threadIdx.x;
    s_ce[tid] = pce[tid];
    s_m[tid]  = pm[tid];
    __syncthreads();
    for (int r = 128; r > 0; r >>= 1) {
        if (tid < r) { s_ce[tid] += s_ce[tid + r]; s_m[tid] += s_m[tid + r]; }
        __syncthreads();
    }
    if (tid == 0) out[0] = s_ce[0] / s_m[0];
}

// ---------------------------------------------------------------------------
extern "C" void kernel_launch(void* const* d_in, const int* in_sizes, int n_in,
                              void* d_out, int out_size, void* d_ws, size_t ws_size,
                              hipStream_t stream)
{
    const int*   tokens = (const int*)d_in[0];
    const int*   labels = (const int*)d_in[1];
    const int*   mask   = (const int*)d_in[2];
    const float* emb    = (const float*)d_in[3];
    const float* Wx     = (const float*)d_in[4];
    const float* Wh     = (const float*)d_in[5];
    const float* bias   = (const float*)d_in[6];
    const float* U      = (const float*)d_in[7];
    const float* b2     = (const float*)d_in[8];

    char* wsb = (char*)d_ws;
    unsigned short* Wswz = (unsigned short*)wsb;                      // 844800 B
    unsigned short* hbuf = (unsigned short*)(wsb + 844800);           // 1245184 B
    float* ce    = (float*)(wsb + 2089984);                           // 491520 B
    float* pce   = (float*)(wsb + 2581504);                           // 1024 B
    float* pm    = (float*)(wsb + 2582528);                           // 1024 B
    int*   flags = (int*)(wsb + 2583552);                             // 122880 B

    hipMemsetAsync(flags, 0, 122880, stream);
    wswz_kernel<<<(NSTRIP * SCOL * NKPAD + 255) / 256, 256, 0, stream>>>(Wx, Wh, Wswz);
    lstm_persist<<<NGRP * NSTRIP, 256, 0, stream>>>(
        tokens, labels, mask, emb, bias, U, b2, Wswz, hbuf, ce, flags);
    reduce1_kernel<<<256, 256, 0, stream>>>(ce, mask, pce, pm);
    reduce2_kernel<<<1, 256, 0, stream>>>(pce, pm, (float*)d_out);
}